// Round 2
// baseline (7530.698 us; speedup 1.0000x reference)
//
#include <hip/hip_runtime.h>
#include <stdint.h>

#define MB 16   // batch rows per group
#define GW 16   // workgroups per group
#define NU 32   // hidden units per WG
#define HD 512
#define SEQ 512
#define DX 40

using short8 = __attribute__((ext_vector_type(8))) short;
using f32x4  = __attribute__((ext_vector_type(4))) float;

__device__ __forceinline__ unsigned short f2bf(float f) {
  uint32_t u = __builtin_bit_cast(uint32_t, f);
  u += 0x7fffu + ((u >> 16) & 1u);
  return (unsigned short)(u >> 16);
}
__device__ __forceinline__ float bf2f(unsigned short s) {
  uint32_t u = ((uint32_t)s) << 16;
  return __builtin_bit_cast(float, u);
}
__device__ __forceinline__ float sigm(float x) { return 1.0f / (1.0f + __expf(-x)); }

// ---------------- GRU persistent kernel ----------------
// grid = 64 (4 groups x 16 WGs), 512 threads. Waves 0..5: MFMA (r,z,n x 2 unit
// tiles), A-fragments loaded DIRECTLY from the global h-exchange buffer (producer
// slice j == K-tile j). Waves 6,7: xn from x only (overlaps the flag wait).
// Barrier: distributed per-WG flags (64B-strided), parallel poll by wave 0.
__global__ __launch_bounds__(512, 2) void gru_kernel(
    const float* __restrict__ x, const float* __restrict__ Wih,
    const float* __restrict__ Whh, const float* __restrict__ bih,
    const float* __restrict__ bhh, unsigned* __restrict__ flags,
    unsigned short* __restrict__ hbuf, float* __restrict__ o1,
    float* __restrict__ stats)
{
  const int wg = blockIdx.x & (GW - 1);
  const int g  = blockIdx.x >> 4;
  const int tid = threadIdx.x;
  const int wave = tid >> 6;
  const int lane = tid & 63;
  const int u0 = wg * NU;
  const int bg = g * MB;

  __shared__ unsigned short x_s[MB][72];   // cols 0..39 = x_t, 40..63 = 0, pad 72
  __shared__ float gate_s[3][MB][NU];
  __shared__ float xn_s[MB][NU];
  __shared__ float wn_s[DX][NU];           // Wih n-gate slice, transposed

  // zero the constant-zero x_s columns once
  for (int i = tid; i < MB * 32; i += 512) x_s[i >> 5][40 + (i & 31)] = 0;
  for (int i = tid; i < DX * NU; i += 512) {
    int c = i >> 5, u = i & 31;
    wn_s[c][u] = Wih[(size_t)(2 * HD + u0 + u) * DX + c];
  }

  // weight B-fragments in registers. B[k][n]: n=lane&15, k=(lane>>4)*8+j.
  short8 bfrag[18];
  const int myGate = wave >> 1;            // 0,1,2 for waves 0..5
  const int ut = wave & 1;
  if (wave < 6) {
    const int row = myGate * HD + u0 + ut * 16 + (lane & 15);
    const int kq = (lane >> 4) * 8;
    for (int kt = 0; kt < 16; ++kt) {
      const float* p = Whh + (size_t)row * HD + kt * 32 + kq;
      short8 f;
#pragma unroll
      for (int j = 0; j < 8; ++j) f[j] = (short)f2bf(p[j]);
      bfrag[kt] = f;
    }
    for (int kt = 16; kt < 18; ++kt) {     // x part: r,z only (n handled by xn_s)
      short8 f;
#pragma unroll
      for (int j = 0; j < 8; ++j) {
        int c = kt * 32 + kq + j - HD;
        float v = (myGate < 2 && c < DX) ? Wih[(size_t)row * DX + c] : 0.0f;
        f[j] = (short)f2bf(v);
      }
      bfrag[kt] = f;
    }
  }

  const int sb = tid >> 5;
  const int su = tid & 31;
  float hprev = 0.0f, ssum = 0.0f, ssq = 0.0f;
  const float b_r  = bih[u0 + su] + bhh[u0 + su];
  const float b_z  = bih[HD + u0 + su] + bhh[HD + u0 + su];
  const float b_in = bih[2 * HD + u0 + su];
  const float b_hn = bhh[2 * HD + u0 + su];

  unsigned* gf = flags + g * GW * 16;      // 64B-strided per-WG flags

  for (int t = 0; t < SEQ; ++t) {
    const unsigned short* hin = hbuf + ((size_t)g * 2 + (t & 1)) * MB * HD;
    unsigned short* hout      = hbuf + ((size_t)g * 2 + ((t + 1) & 1)) * MB * HD;
    {  // stage x_t (no h dependency — overlaps the wait)
      int b = tid >> 5, c = tid & 31;
      const float* xr = x + ((size_t)(bg + b) * SEQ + t) * DX;
      x_s[b][c] = f2bf(xr[c]);
      if (c < 8) x_s[b][32 + c] = f2bf(xr[32 + c]);
    }
    if (wave == 0) {                       // parallel distributed-flag wait
      if (lane < GW && lane != wg) {
        const unsigned* f = gf + lane * 16;
        while (__hip_atomic_load(f, __ATOMIC_RELAXED, __HIP_MEMORY_SCOPE_AGENT) <
               (unsigned)t) {}
      }
      __threadfence();                     // acquire: invalidate L1/L2
    }
    __syncthreads();  // A: h_t visible, x_s staged

    if (wave < 6) {
      const int m = lane & 15;
      const int kq = (lane >> 4) * 8;
      const unsigned short* hrow = hin + m * HD + kq;
      f32x4 acc = {0.f, 0.f, 0.f, 0.f};
      short8 a[8];
#pragma unroll
      for (int k = 0; k < 8; ++k) a[k] = *(const short8*)(hrow + k * 32);
#pragma unroll
      for (int k = 0; k < 8; ++k)
        acc = __builtin_amdgcn_mfma_f32_16x16x32_bf16(a[k], bfrag[k], acc, 0, 0, 0);
#pragma unroll
      for (int k = 0; k < 8; ++k) a[k] = *(const short8*)(hrow + (8 + k) * 32);
#pragma unroll
      for (int k = 0; k < 8; ++k)
        acc = __builtin_amdgcn_mfma_f32_16x16x32_bf16(a[k], bfrag[8 + k], acc, 0, 0, 0);
      short8 ax0 = *(const short8*)(&x_s[m][kq]);
      short8 ax1 = *(const short8*)(&x_s[m][32 + kq]);
      acc = __builtin_amdgcn_mfma_f32_16x16x32_bf16(ax0, bfrag[16], acc, 0, 0, 0);
      acc = __builtin_amdgcn_mfma_f32_16x16x32_bf16(ax1, bfrag[17], acc, 0, 0, 0);
#pragma unroll
      for (int r = 0; r < 4; ++r)          // C/D: col=lane&15, row=(lane>>4)*4+r
        gate_s[myGate][(lane >> 4) * 4 + r][ut * 16 + (lane & 15)] = acc[r];
    } else {
      int base = (tid - 384) * 4;
#pragma unroll
      for (int i = 0; i < 4; ++i) {
        int idx = base + i, b = idx >> 5, u = idx & 31;
        float s = 0.0f;
        for (int c = 0; c < DX; ++c) s += bf2f(x_s[b][c]) * wn_s[c][u];
        xn_s[b][u] = s;
      }
    }
    __syncthreads();  // B: gates + xn ready

    float r_ = sigm(gate_s[0][sb][su] + b_r);
    float z_ = sigm(gate_s[1][sb][su] + b_z);
    float n_ = tanhf(xn_s[sb][su] + b_in + r_ * (gate_s[2][sb][su] + b_hn));
    float h = (1.0f - z_) * n_ + z_ * hprev;
    hprev = h;
    ssum += h; ssq += h * h;
    hout[sb * HD + u0 + su] = f2bf(h);
    __syncthreads();  // C: all hout stores in L2

    if (tid == 0) {
      __threadfence();                     // release: wbl2 -> LLC
      __hip_atomic_store(gf + wg * 16, (unsigned)(t + 1), __ATOMIC_RELAXED,
                         __HIP_MEMORY_SCOPE_AGENT);
    }
    // o1 store AFTER publish — drain overlaps next step's wait
    o1[((size_t)(bg + sb) * SEQ + t) * HD + u0 + su] = h;
  }

  atomicAdd(&stats[u0 + su], ssum);
  atomicAdd(&stats[HD + u0 + su], ssq);
}

// ---------------- LSTM persistent kernel ----------------
// 8 MFMA waves (i,f,g,o x 2 unit tiles); x(40)+ssr(1) folded into K-tiles 16,17.
__global__ __launch_bounds__(512, 2) void lstm_kernel(
    const float* __restrict__ x, const float* __restrict__ Wih,
    const float* __restrict__ Whh, const float* __restrict__ bih,
    const float* __restrict__ bhh, const float* __restrict__ ssr,
    unsigned* __restrict__ flags, unsigned short* __restrict__ hbuf,
    float* __restrict__ o2)
{
  const int wg = blockIdx.x & (GW - 1);
  const int g  = blockIdx.x >> 4;
  const int tid = threadIdx.x;
  const int wave = tid >> 6;
  const int lane = tid & 63;
  const int u0 = wg * NU;
  const int bg = g * MB;

  __shared__ unsigned short x_s[MB][72];   // 0..39 x, 40 ssr, 41..63 zero
  __shared__ float gate_s[4][MB][NU];

  for (int i = tid; i < MB * 32; i += 512) x_s[i >> 5][40 + (i & 31)] = 0;

  short8 bfrag[18];
  const int myGate = wave >> 1;
  const int ut = wave & 1;
  {
    const int row = myGate * HD + u0 + ut * 16 + (lane & 15);
    const int kq = (lane >> 4) * 8;
    for (int kt = 0; kt < 16; ++kt) {
      const float* p = Whh + (size_t)row * HD + kt * 32 + kq;
      short8 f;
#pragma unroll
      for (int j = 0; j < 8; ++j) f[j] = (short)f2bf(p[j]);
      bfrag[kt] = f;
    }
    for (int kt = 16; kt < 18; ++kt) {     // Wih has 41 cols (x, ssr)
      short8 f;
#pragma unroll
      for (int j = 0; j < 8; ++j) {
        int c = kt * 32 + kq + j - HD;
        float v = (c < 41) ? Wih[(size_t)row * 41 + c] : 0.0f;
        f[j] = (short)f2bf(v);
      }
      bfrag[kt] = f;
    }
  }

  const int sb = tid >> 5;
  const int su = tid & 31;
  float creg = 0.0f;
  const float b_i = bih[u0 + su] + bhh[u0 + su];
  const float b_f = bih[HD + u0 + su] + bhh[HD + u0 + su];
  const float b_g = bih[2 * HD + u0 + su] + bhh[2 * HD + u0 + su];
  const float b_o = bih[3 * HD + u0 + su] + bhh[3 * HD + u0 + su];

  unsigned* gf = flags + g * GW * 16;

  for (int t = 0; t < SEQ; ++t) {
    const unsigned short* hin = hbuf + ((size_t)g * 2 + (t & 1)) * MB * HD;
    unsigned short* hout      = hbuf + ((size_t)g * 2 + ((t + 1) & 1)) * MB * HD;
    {
      int b = tid >> 5, c = tid & 31;
      const float* xr = x + ((size_t)(bg + b) * SEQ + t) * DX;
      x_s[b][c] = f2bf(xr[c]);
      if (c < 8) x_s[b][32 + c] = f2bf(xr[32 + c]);
      if (c == 8) x_s[b][40] = f2bf(ssr[(size_t)(bg + b) * SEQ + t]);
    }
    if (wave == 0) {
      if (lane < GW && lane != wg) {
        const unsigned* f = gf + lane * 16;
        while (__hip_atomic_load(f, __ATOMIC_RELAXED, __HIP_MEMORY_SCOPE_AGENT) <
               (unsigned)t) {}
      }
      __threadfence();
    }
    __syncthreads();  // A

    {
      const int m = lane & 15;
      const int kq = (lane >> 4) * 8;
      const unsigned short* hrow = hin + m * HD + kq;
      f32x4 acc = {0.f, 0.f, 0.f, 0.f};
      short8 a[8];
#pragma unroll
      for (int k = 0; k < 8; ++k) a[k] = *(const short8*)(hrow + k * 32);
#pragma unroll
      for (int k = 0; k < 8; ++k)
        acc = __builtin_amdgcn_mfma_f32_16x16x32_bf16(a[k], bfrag[k], acc, 0, 0, 0);
#pragma unroll
      for (int k = 0; k < 8; ++k) a[k] = *(const short8*)(hrow + (8 + k) * 32);
#pragma unroll
      for (int k = 0; k < 8; ++k)
        acc = __builtin_amdgcn_mfma_f32_16x16x32_bf16(a[k], bfrag[8 + k], acc, 0, 0, 0);
      short8 ax0 = *(const short8*)(&x_s[m][kq]);
      short8 ax1 = *(const short8*)(&x_s[m][32 + kq]);
      acc = __builtin_amdgcn_mfma_f32_16x16x32_bf16(ax0, bfrag[16], acc, 0, 0, 0);
      acc = __builtin_amdgcn_mfma_f32_16x16x32_bf16(ax1, bfrag[17], acc, 0, 0, 0);
#pragma unroll
      for (int r = 0; r < 4; ++r)
        gate_s[myGate][(lane >> 4) * 4 + r][ut * 16 + (lane & 15)] = acc[r];
    }
    __syncthreads();  // B

    float gi = sigm(gate_s[0][sb][su] + b_i);
    float gf_ = sigm(gate_s[1][sb][su] + b_f);
    float gg = tanhf(gate_s[2][sb][su] + b_g);
    float go = sigm(gate_s[3][sb][su] + b_o);
    creg = gf_ * creg + gi * gg;
    float h = go * tanhf(creg);
    hout[sb * HD + u0 + su] = f2bf(h);
    __syncthreads();  // C

    if (tid == 0) {
      __threadfence();
      __hip_atomic_store(gf + wg * 16, (unsigned)(t + 1), __ATOMIC_RELAXED,
                         __HIP_MEMORY_SCOPE_AGENT);
    }
    o2[((size_t)(bg + sb) * SEQ + t) * HD + u0 + su] = h;
  }
}

// ---------------- BN-coefficient kernel (1 block) ----------------
__global__ __launch_bounds__(512) void coef_kernel(
    const float* __restrict__ stats, const float* __restrict__ fc1_w,
    const float* __restrict__ fc1_b, const float* __restrict__ fc2_w,
    const float* __restrict__ fc2_b, const float* __restrict__ gamma,
    const float* __restrict__ beta, float* __restrict__ coef)
{
  __shared__ float r1[512], r2[512];
  const int j = threadIdx.x;
  const float inv_n = 1.0f / 32768.0f;
  float mean = stats[j] * inv_n;
  float var = stats[HD + j] * inv_n - mean * mean;
  float scale = gamma[j] * rsqrtf(var + 1e-5f);
  float shift = beta[j] - mean * scale;
  coef[j] = fc1_w[j] * scale;
  coef[HD + j] = fc2_w[j] * scale;
  r1[j] = fc1_w[j] * shift;
  r2[j] = fc2_w[j] * shift;
  __syncthreads();
  for (int s = 256; s > 0; s >>= 1) {
    if (j < s) { r1[j] += r1[j + s]; r2[j] += r2[j + s]; }
    __syncthreads();
  }
  if (j == 0) {
    coef[2 * HD] = r1[0] + fc1_b[0];
    coef[2 * HD + 1] = r2[0] + fc2_b[0];
  }
}

// ---------------- ssr kernel: one wave per (b,t) row ----------------
__global__ __launch_bounds__(256) void ssr_kernel(
    const float* __restrict__ o1, const float* __restrict__ coef,
    float* __restrict__ ssr_ws, float* __restrict__ dssr)
{
  const int row = blockIdx.x * 4 + (threadIdx.x >> 6);
  const int lane = threadIdx.x & 63;
  const float* p = o1 + (size_t)row * HD + lane * 8;
  float s1 = 0.f, s2 = 0.f;
#pragma unroll
  for (int j = 0; j < 8; ++j) {
    float v = p[j];
    s1 += v * coef[lane * 8 + j];
    s2 += v * coef[HD + lane * 8 + j];
  }
#pragma unroll
  for (int off = 32; off > 0; off >>= 1) {
    s1 += __shfl_down(s1, off);
    s2 += __shfl_down(s2, off);
  }
  if (lane == 0) {
    float sr = fmaxf(s1 + coef[2 * HD], 0.0f);
    float w = fabsf(sigm(s2 + coef[2 * HD + 1]));
    float v = sr * (1.0f + w);
    ssr_ws[row] = v;
    dssr[row] = v;
  }
}

// ---------------- fc3 output kernel ----------------
__global__ __launch_bounds__(256) void out_kernel(
    const float* __restrict__ o2, const float* __restrict__ fc3_w,
    const float* __restrict__ fc3_b, float* __restrict__ dout)
{
  const int row = blockIdx.x * 4 + (threadIdx.x >> 6);
  const int lane = threadIdx.x & 63;
  const float* p = o2 + (size_t)row * HD + lane * 8;
  float s = 0.f;
#pragma unroll
  for (int j = 0; j < 8; ++j) s += p[j] * fc3_w[lane * 8 + j];
#pragma unroll
  for (int off = 32; off > 0; off >>= 1) s += __shfl_down(s, off);
  if (lane == 0) dout[row] = fmaxf(s + fc3_b[0], 0.0f);
}

extern "C" void kernel_launch(void* const* d_in, const int* in_sizes, int n_in,
                              void* d_out, int out_size, void* d_ws, size_t ws_size,
                              hipStream_t stream) {
  (void)in_sizes; (void)n_in; (void)out_size; (void)ws_size;
  const float* x    = (const float*)d_in[0];
  const float* gWih = (const float*)d_in[1];
  const float* gWhh = (const float*)d_in[2];
  const float* gbih = (const float*)d_in[3];
  const float* gbhh = (const float*)d_in[4];
  const float* lWih = (const float*)d_in[5];
  const float* lWhh = (const float*)d_in[6];
  const float* lbih = (const float*)d_in[7];
  const float* lbhh = (const float*)d_in[8];
  const float* fc1w = (const float*)d_in[9];
  const float* fc1b = (const float*)d_in[10];
  const float* fc2w = (const float*)d_in[11];
  const float* fc2b = (const float*)d_in[12];
  const float* fc3w = (const float*)d_in[13];
  const float* fc3b = (const float*)d_in[14];
  const float* gam  = (const float*)d_in[15];
  const float* bet  = (const float*)d_in[16];
  float* out = (float*)d_out;

  char* ws = (char*)d_ws;
  unsigned* flags_g = (unsigned*)(ws + 0);           // 4 groups x 16 WG x 64B
  unsigned* flags_l = (unsigned*)(ws + 4096);
  float* stats      = (float*)(ws + 8192);           // 1024 f32
  float* coef       = (float*)(ws + 16384);          // 1026 f32
  float* ssr_ws     = (float*)(ws + 32768);          // 32768 f32
  unsigned short* hbuf_g = (unsigned short*)(ws + 65536);    // 128KB
  unsigned short* hbuf_l = (unsigned short*)(ws + 196608);   // 128KB
  float* o1 = (float*)(ws + 327680);                 // 64MB
  float* o2 = o1 + (size_t)64 * SEQ * HD;            // 64MB

  hipMemsetAsync(ws, 0, 12288, stream);              // flags + stats
  hipMemsetAsync(ws + 65536, 0, 262144, stream);     // h exchange buffers (h0=0)

  gru_kernel<<<dim3(64), dim3(512), 0, stream>>>(x, gWih, gWhh, gbih, gbhh,
                                                 flags_g, hbuf_g, o1, stats);
  coef_kernel<<<dim3(1), dim3(512), 0, stream>>>(stats, fc1w, fc1b, fc2w, fc2b,
                                                 gam, bet, coef);
  ssr_kernel<<<dim3(8192), dim3(256), 0, stream>>>(o1, coef, ssr_ws, out + 32768);
  lstm_kernel<<<dim3(64), dim3(512), 0, stream>>>(x, lWih, lWhh, lbih, lbhh, ssr_ws,
                                                  flags_l, hbuf_l, o2);
  out_kernel<<<dim3(8192), dim3(256), 0, stream>>>(o2, fc3w, fc3b, out);
}

// Round 3
// 3505.154 us; speedup vs baseline: 2.1485x; 2.1485x over previous
//
#include <hip/hip_runtime.h>
#include <stdint.h>

#define MB 16   // batch rows per group
#define GW 16   // workgroups per group
#define NU 32   // hidden units per WG
#define HD 512
#define SEQ 512
#define DX 40

using short8 = __attribute__((ext_vector_type(8))) short;
using f32x4  = __attribute__((ext_vector_type(4))) float;

__device__ __forceinline__ unsigned short f2bf(float f) {
  uint32_t u = __builtin_bit_cast(uint32_t, f);
  u += 0x7fffu + ((u >> 16) & 1u);
  return (unsigned short)(u >> 16);
}
__device__ __forceinline__ float bf2f(unsigned short s) {
  uint32_t u = ((uint32_t)s) << 16;
  return __builtin_bit_cast(float, u);
}
__device__ __forceinline__ float sigm(float x) { return 1.0f / (1.0f + __expf(-x)); }

// h exchange protocol (both recurrent kernels):
//  - hout: bf16x2 packed, stored with __hip_atomic_store (relaxed, AGENT) ->
//    global_store sc0 sc1: write-through to LLC. No threadfence needed.
//  - __syncthreads() drains vmcnt -> stores are AT the LLC before the flag store.
//  - flag: relaxed agent atomic store; consumers poll with relaxed agent atomic
//    loads (sc0 sc1 -> read LLC directly, no buffer_inv, L1/L2 stay warm for x/w).
//  - staging: 4x 8B atomic loads/thread -> bf16 LDS tile, one LLC round trip.

// ---------------- GRU persistent kernel ----------------
// grid = 64 (4 groups x 16 WGs), 512 threads. Waves 0..5: MFMA (r,z,n x 2 unit
// tiles). Waves 6,7: xn from x only (n = tanh(xn + r*hn) needs xn separate).
__global__ __launch_bounds__(512, 2) void gru_kernel(
    const float* __restrict__ x, const float* __restrict__ Wih,
    const float* __restrict__ Whh, const float* __restrict__ bih,
    const float* __restrict__ bhh, unsigned* __restrict__ flags,
    unsigned short* __restrict__ hbuf, float* __restrict__ o1,
    float* __restrict__ stats)
{
  const int wg = blockIdx.x & (GW - 1);
  const int g  = blockIdx.x >> 4;
  const int tid = threadIdx.x;
  const int wave = tid >> 6;
  const int lane = tid & 63;
  const int u0 = wg * NU;
  const int bg = g * MB;

  __shared__ unsigned short h_s[MB][520];  // bf16 h tile, stride 520
  __shared__ unsigned short x_s[MB][72];   // 0..39 x, 40..63 zero
  __shared__ float gate_s[3][MB][NU];
  __shared__ float xn_s[MB][NU];
  __shared__ float wn_s[DX][NU];           // Wih n-gate slice, transposed

  for (int i = tid; i < MB * 32; i += 512) x_s[i >> 5][40 + (i & 31)] = 0;
  for (int i = tid; i < DX * NU; i += 512) {
    int c = i >> 5, u = i & 31;
    wn_s[c][u] = Wih[(size_t)(2 * HD + u0 + u) * DX + c];
  }

  // weight B-fragments in registers. B[k][n]: n=lane&15, k=(lane>>4)*8+j.
  short8 bfrag[18];
  const int myGate = wave >> 1;
  const int ut = wave & 1;
  if (wave < 6) {
    const int row = myGate * HD + u0 + ut * 16 + (lane & 15);
    const int kq = (lane >> 4) * 8;
    for (int kt = 0; kt < 16; ++kt) {
      const float* p = Whh + (size_t)row * HD + kt * 32 + kq;
      short8 f;
#pragma unroll
      for (int j = 0; j < 8; ++j) f[j] = (short)f2bf(p[j]);
      bfrag[kt] = f;
    }
    for (int kt = 16; kt < 18; ++kt) {     // x part: r,z only (n via xn_s)
      short8 f;
#pragma unroll
      for (int j = 0; j < 8; ++j) {
        int c = kt * 32 + kq + j - HD;
        float v = (myGate < 2 && c < DX) ? Wih[(size_t)row * DX + c] : 0.0f;
        f[j] = (short)f2bf(v);
      }
      bfrag[kt] = f;
    }
  }

  const int sb = tid >> 5;
  const int su = tid & 31;
  float hprev = 0.0f, ssum = 0.0f, ssq = 0.0f;
  const float b_r  = bih[u0 + su] + bhh[u0 + su];
  const float b_z  = bih[HD + u0 + su] + bhh[HD + u0 + su];
  const float b_in = bih[2 * HD + u0 + su];
  const float b_hn = bhh[2 * HD + u0 + su];

  unsigned* gf = flags + g * GW * 16;      // 64B-strided per-WG flags

  for (int t = 0; t < SEQ; ++t) {
    const unsigned long long* hin64 =
        (const unsigned long long*)(hbuf + ((size_t)g * 2 + (t & 1)) * MB * HD);
    uint32_t* hout32 =
        (uint32_t*)(hbuf + ((size_t)g * 2 + ((t + 1) & 1)) * MB * HD);

    {  // stage x_t (no h dependency — overlaps the wait)
      int b = tid >> 5, c = tid & 31;
      const float* xr = x + ((size_t)(bg + b) * SEQ + t) * DX;
      x_s[b][c] = f2bf(xr[c]);
      if (c < 8) x_s[b][32 + c] = f2bf(xr[32 + c]);
    }
    if (wave == 0 && lane < GW && lane != wg) {   // distributed-flag wait
      const unsigned* f = gf + lane * 16;
      while (__hip_atomic_load(f, __ATOMIC_RELAXED, __HIP_MEMORY_SCOPE_AGENT) <
             (unsigned)t)
        __builtin_amdgcn_s_sleep(1);
    }
    __syncthreads();  // A: flags seen

    {  // stage h: 4 x 8B LLC loads/thread -> LDS (coalesced)
#pragma unroll
      for (int it = 0; it < 4; ++it) {
        int q = it * 512 + tid;            // uint64 index into 16KB tile
        unsigned long long v = __hip_atomic_load(hin64 + q, __ATOMIC_RELAXED,
                                                 __HIP_MEMORY_SCOPE_AGENT);
        int b = q >> 7, c = (q & 127) * 4;
        *(unsigned long long*)(&h_s[b][c]) = v;
      }
    }
    __syncthreads();  // B: h_s ready

    if (wave < 6) {
      const int m = lane & 15;
      const int kq = (lane >> 4) * 8;
      f32x4 acc = {0.f, 0.f, 0.f, 0.f};
#pragma unroll
      for (int kt = 0; kt < 16; ++kt) {
        short8 a = *(const short8*)(&h_s[m][kt * 32 + kq]);
        acc = __builtin_amdgcn_mfma_f32_16x16x32_bf16(a, bfrag[kt], acc, 0, 0, 0);
      }
      short8 ax0 = *(const short8*)(&x_s[m][kq]);
      short8 ax1 = *(const short8*)(&x_s[m][32 + kq]);
      acc = __builtin_amdgcn_mfma_f32_16x16x32_bf16(ax0, bfrag[16], acc, 0, 0, 0);
      acc = __builtin_amdgcn_mfma_f32_16x16x32_bf16(ax1, bfrag[17], acc, 0, 0, 0);
#pragma unroll
      for (int r = 0; r < 4; ++r)          // C/D: col=lane&15, row=(lane>>4)*4+r
        gate_s[myGate][(lane >> 4) * 4 + r][ut * 16 + (lane & 15)] = acc[r];
    } else {
      int base = (tid - 384) * 4;
#pragma unroll
      for (int i = 0; i < 4; ++i) {
        int idx = base + i, b = idx >> 5, u = idx & 31;
        float s = 0.0f;
        for (int c = 0; c < DX; ++c) s += bf2f(x_s[b][c]) * wn_s[c][u];
        xn_s[b][u] = s;
      }
    }
    __syncthreads();  // C: gates + xn ready

    float r_ = sigm(gate_s[0][sb][su] + b_r);
    float z_ = sigm(gate_s[1][sb][su] + b_z);
    float n_ = tanhf(xn_s[sb][su] + b_in + r_ * (gate_s[2][sb][su] + b_hn));
    float h = (1.0f - z_) * n_ + z_ * hprev;
    hprev = h;
    ssum += h; ssq += h * h;
    {  // pack bf16x2 with lane partner, even threads write-through to LLC
      float hp = __shfl_xor(h, 1);
      if ((tid & 1) == 0) {
        uint32_t packed = (uint32_t)f2bf(h) | ((uint32_t)f2bf(hp) << 16);
        __hip_atomic_store(hout32 + ((sb * HD + u0 + su) >> 1), packed,
                           __ATOMIC_RELAXED, __HIP_MEMORY_SCOPE_AGENT);
      }
    }
    __syncthreads();  // D: drains vmcnt -> hout committed at LLC

    if (tid == 0)
      __hip_atomic_store(gf + wg * 16, (unsigned)(t + 1), __ATOMIC_RELAXED,
                         __HIP_MEMORY_SCOPE_AGENT);
    o1[((size_t)(bg + sb) * SEQ + t) * HD + u0 + su] = h;
  }

  atomicAdd(&stats[u0 + su], ssum);
  atomicAdd(&stats[HD + u0 + su], ssq);
}

// ---------------- LSTM persistent kernel ----------------
// 8 MFMA waves (i,f,g,o x 2 unit tiles); x(40)+ssr(1) folded into K-tiles 16,17.
__global__ __launch_bounds__(512, 2) void lstm_kernel(
    const float* __restrict__ x, const float* __restrict__ Wih,
    const float* __restrict__ Whh, const float* __restrict__ bih,
    const float* __restrict__ bhh, const float* __restrict__ ssr,
    unsigned* __restrict__ flags, unsigned short* __restrict__ hbuf,
    float* __restrict__ o2)
{
  const int wg = blockIdx.x & (GW - 1);
  const int g  = blockIdx.x >> 4;
  const int tid = threadIdx.x;
  const int wave = tid >> 6;
  const int lane = tid & 63;
  const int u0 = wg * NU;
  const int bg = g * MB;

  __shared__ unsigned short h_s[MB][520];
  __shared__ unsigned short x_s[MB][72];   // 0..39 x, 40 ssr, 41..63 zero
  __shared__ float gate_s[4][MB][NU];

  for (int i = tid; i < MB * 32; i += 512) x_s[i >> 5][40 + (i & 31)] = 0;

  short8 bfrag[18];
  const int myGate = wave >> 1;
  const int ut = wave & 1;
  {
    const int row = myGate * HD + u0 + ut * 16 + (lane & 15);
    const int kq = (lane >> 4) * 8;
    for (int kt = 0; kt < 16; ++kt) {
      const float* p = Whh + (size_t)row * HD + kt * 32 + kq;
      short8 f;
#pragma unroll
      for (int j = 0; j < 8; ++j) f[j] = (short)f2bf(p[j]);
      bfrag[kt] = f;
    }
    for (int kt = 16; kt < 18; ++kt) {     // Wih has 41 cols (x, ssr)
      short8 f;
#pragma unroll
      for (int j = 0; j < 8; ++j) {
        int c = kt * 32 + kq + j - HD;
        float v = (c < 41) ? Wih[(size_t)row * 41 + c] : 0.0f;
        f[j] = (short)f2bf(v);
      }
      bfrag[kt] = f;
    }
  }

  const int sb = tid >> 5;
  const int su = tid & 31;
  float creg = 0.0f;
  const float b_i = bih[u0 + su] + bhh[u0 + su];
  const float b_f = bih[HD + u0 + su] + bhh[HD + u0 + su];
  const float b_g = bih[2 * HD + u0 + su] + bhh[2 * HD + u0 + su];
  const float b_o = bih[3 * HD + u0 + su] + bhh[3 * HD + u0 + su];

  unsigned* gf = flags + g * GW * 16;

  for (int t = 0; t < SEQ; ++t) {
    const unsigned long long* hin64 =
        (const unsigned long long*)(hbuf + ((size_t)g * 2 + (t & 1)) * MB * HD);
    uint32_t* hout32 =
        (uint32_t*)(hbuf + ((size_t)g * 2 + ((t + 1) & 1)) * MB * HD);

    {
      int b = tid >> 5, c = tid & 31;
      const float* xr = x + ((size_t)(bg + b) * SEQ + t) * DX;
      x_s[b][c] = f2bf(xr[c]);
      if (c < 8) x_s[b][32 + c] = f2bf(xr[32 + c]);
      if (c == 8) x_s[b][40] = f2bf(ssr[(size_t)(bg + b) * SEQ + t]);
    }
    if (wave == 0 && lane < GW && lane != wg) {
      const unsigned* f = gf + lane * 16;
      while (__hip_atomic_load(f, __ATOMIC_RELAXED, __HIP_MEMORY_SCOPE_AGENT) <
             (unsigned)t)
        __builtin_amdgcn_s_sleep(1);
    }
    __syncthreads();  // A

    {
#pragma unroll
      for (int it = 0; it < 4; ++it) {
        int q = it * 512 + tid;
        unsigned long long v = __hip_atomic_load(hin64 + q, __ATOMIC_RELAXED,
                                                 __HIP_MEMORY_SCOPE_AGENT);
        int b = q >> 7, c = (q & 127) * 4;
        *(unsigned long long*)(&h_s[b][c]) = v;
      }
    }
    __syncthreads();  // B

    {
      const int m = lane & 15;
      const int kq = (lane >> 4) * 8;
      f32x4 acc = {0.f, 0.f, 0.f, 0.f};
#pragma unroll
      for (int kt = 0; kt < 16; ++kt) {
        short8 a = *(const short8*)(&h_s[m][kt * 32 + kq]);
        acc = __builtin_amdgcn_mfma_f32_16x16x32_bf16(a, bfrag[kt], acc, 0, 0, 0);
      }
      short8 ax0 = *(const short8*)(&x_s[m][kq]);
      short8 ax1 = *(const short8*)(&x_s[m][32 + kq]);
      acc = __builtin_amdgcn_mfma_f32_16x16x32_bf16(ax0, bfrag[16], acc, 0, 0, 0);
      acc = __builtin_amdgcn_mfma_f32_16x16x32_bf16(ax1, bfrag[17], acc, 0, 0, 0);
#pragma unroll
      for (int r = 0; r < 4; ++r)
        gate_s[myGate][(lane >> 4) * 4 + r][ut * 16 + (lane & 15)] = acc[r];
    }
    __syncthreads();  // C

    float gi = sigm(gate_s[0][sb][su] + b_i);
    float gf_ = sigm(gate_s[1][sb][su] + b_f);
    float gg = tanhf(gate_s[2][sb][su] + b_g);
    float go = sigm(gate_s[3][sb][su] + b_o);
    creg = gf_ * creg + gi * gg;
    float h = go * tanhf(creg);
    {
      float hp = __shfl_xor(h, 1);
      if ((tid & 1) == 0) {
        uint32_t packed = (uint32_t)f2bf(h) | ((uint32_t)f2bf(hp) << 16);
        __hip_atomic_store(hout32 + ((sb * HD + u0 + su) >> 1), packed,
                           __ATOMIC_RELAXED, __HIP_MEMORY_SCOPE_AGENT);
      }
    }
    __syncthreads();  // D

    if (tid == 0)
      __hip_atomic_store(gf + wg * 16, (unsigned)(t + 1), __ATOMIC_RELAXED,
                         __HIP_MEMORY_SCOPE_AGENT);
    o2[((size_t)(bg + sb) * SEQ + t) * HD + u0 + su] = h;
  }
}

// ---------------- BN-coefficient kernel (1 block) ----------------
__global__ __launch_bounds__(512) void coef_kernel(
    const float* __restrict__ stats, const float* __restrict__ fc1_w,
    const float* __restrict__ fc1_b, const float* __restrict__ fc2_w,
    const float* __restrict__ fc2_b, const float* __restrict__ gamma,
    const float* __restrict__ beta, float* __restrict__ coef)
{
  __shared__ float r1[512], r2[512];
  const int j = threadIdx.x;
  const float inv_n = 1.0f / 32768.0f;
  float mean = stats[j] * inv_n;
  float var = stats[HD + j] * inv_n - mean * mean;
  float scale = gamma[j] * rsqrtf(var + 1e-5f);
  float shift = beta[j] - mean * scale;
  coef[j] = fc1_w[j] * scale;
  coef[HD + j] = fc2_w[j] * scale;
  r1[j] = fc1_w[j] * shift;
  r2[j] = fc2_w[j] * shift;
  __syncthreads();
  for (int s = 256; s > 0; s >>= 1) {
    if (j < s) { r1[j] += r1[j + s]; r2[j] += r2[j + s]; }
    __syncthreads();
  }
  if (j == 0) {
    coef[2 * HD] = r1[0] + fc1_b[0];
    coef[2 * HD + 1] = r2[0] + fc2_b[0];
  }
}

// ---------------- ssr kernel: one wave per (b,t) row ----------------
__global__ __launch_bounds__(256) void ssr_kernel(
    const float* __restrict__ o1, const float* __restrict__ coef,
    float* __restrict__ ssr_ws, float* __restrict__ dssr)
{
  const int row = blockIdx.x * 4 + (threadIdx.x >> 6);
  const int lane = threadIdx.x & 63;
  const float* p = o1 + (size_t)row * HD + lane * 8;
  float s1 = 0.f, s2 = 0.f;
#pragma unroll
  for (int j = 0; j < 8; ++j) {
    float v = p[j];
    s1 += v * coef[lane * 8 + j];
    s2 += v * coef[HD + lane * 8 + j];
  }
#pragma unroll
  for (int off = 32; off > 0; off >>= 1) {
    s1 += __shfl_down(s1, off);
    s2 += __shfl_down(s2, off);
  }
  if (lane == 0) {
    float sr = fmaxf(s1 + coef[2 * HD], 0.0f);
    float w = fabsf(sigm(s2 + coef[2 * HD + 1]));
    float v = sr * (1.0f + w);
    ssr_ws[row] = v;
    dssr[row] = v;
  }
}

// ---------------- fc3 output kernel ----------------
__global__ __launch_bounds__(256) void out_kernel(
    const float* __restrict__ o2, const float* __restrict__ fc3_w,
    const float* __restrict__ fc3_b, float* __restrict__ dout)
{
  const int row = blockIdx.x * 4 + (threadIdx.x >> 6);
  const int lane = threadIdx.x & 63;
  const float* p = o2 + (size_t)row * HD + lane * 8;
  float s = 0.f;
#pragma unroll
  for (int j = 0; j < 8; ++j) s += p[j] * fc3_w[lane * 8 + j];
#pragma unroll
  for (int off = 32; off > 0; off >>= 1) s += __shfl_down(s, off);
  if (lane == 0) dout[row] = fmaxf(s + fc3_b[0], 0.0f);
}

extern "C" void kernel_launch(void* const* d_in, const int* in_sizes, int n_in,
                              void* d_out, int out_size, void* d_ws, size_t ws_size,
                              hipStream_t stream) {
  (void)in_sizes; (void)n_in; (void)out_size; (void)ws_size;
  const float* x    = (const float*)d_in[0];
  const float* gWih = (const float*)d_in[1];
  const float* gWhh = (const float*)d_in[2];
  const float* gbih = (const float*)d_in[3];
  const float* gbhh = (const float*)d_in[4];
  const float* lWih = (const float*)d_in[5];
  const float* lWhh = (const float*)d_in[6];
  const float* lbih = (const float*)d_in[7];
  const float* lbhh = (const float*)d_in[8];
  const float* fc1w = (const float*)d_in[9];
  const float* fc1b = (const float*)d_in[10];
  const float* fc2w = (const float*)d_in[11];
  const float* fc2b = (const float*)d_in[12];
  const float* fc3w = (const float*)d_in[13];
  const float* fc3b = (const float*)d_in[14];
  const float* gam  = (const float*)d_in[15];
  const float* bet  = (const float*)d_in[16];
  float* out = (float*)d_out;

  char* ws = (char*)d_ws;
  unsigned* flags_g = (unsigned*)(ws + 0);           // 4 groups x 16 WG x 64B
  unsigned* flags_l = (unsigned*)(ws + 4096);
  float* stats      = (float*)(ws + 8192);           // 1024 f32
  float* coef       = (float*)(ws + 16384);          // 1026 f32
  float* ssr_ws     = (float*)(ws + 32768);          // 32768 f32
  unsigned short* hbuf_g = (unsigned short*)(ws + 65536);    // 128KB
  unsigned short* hbuf_l = (unsigned short*)(ws + 196608);   // 128KB
  float* o1 = (float*)(ws + 327680);                 // 64MB
  float* o2 = o1 + (size_t)64 * SEQ * HD;            // 64MB

  hipMemsetAsync(ws, 0, 12288, stream);              // flags + stats
  hipMemsetAsync(ws + 65536, 0, 262144, stream);     // h exchange buffers (h0=0)

  gru_kernel<<<dim3(64), dim3(512), 0, stream>>>(x, gWih, gWhh, gbih, gbhh,
                                                 flags_g, hbuf_g, o1, stats);
  coef_kernel<<<dim3(1), dim3(512), 0, stream>>>(stats, fc1w, fc1b, fc2w, fc2b,
                                                 gam, bet, coef);
  ssr_kernel<<<dim3(8192), dim3(256), 0, stream>>>(o1, coef, ssr_ws, out + 32768);
  lstm_kernel<<<dim3(64), dim3(512), 0, stream>>>(x, lWih, lWhh, lbih, lbhh, ssr_ws,
                                                  flags_l, hbuf_l, o2);
  out_kernel<<<dim3(8192), dim3(256), 0, stream>>>(o2, fc3w, fc3b, out);
}